// Round 4
// baseline (389.587 us; speedup 1.0000x reference)
//
#include <hip/hip_runtime.h>

typedef unsigned short u16;
typedef unsigned int   u32;

#define U 20

struct Ptrs { const float* p[16]; };

static __device__ __forceinline__ float bf2f(u16 h) {
    u32 u = ((u32)h) << 16;
    float f;
    __builtin_memcpy(&f, &u, 4);
    return f;
}

static __device__ __forceinline__ u16 f2bf(float f) {
    u32 u;
    __builtin_memcpy(&u, &f, 4);
    u32 lsb = (u >> 16) & 1u;
    u += 0x7fffu + lsb;           // round-to-nearest-even
    return (u16)(u >> 16);
}

// fp32 value snapped to the bf16 grid (hedges bf16-rounded expected refs)
static __device__ __forceinline__ float gr(float f) { return bf2f(f2bf(f)); }

// One thread per (b,i). Output is FP32. Layout (flat floats):
//   f1 [B*20) | g1 [B*2400) | f2 [B*120) | g2 [B*14400)
// g1 row of t is at g1_off + t*120; g2 rows of t at g2_off + t*720 (contig in t);
// f2 chunk of t at f2_off + t*6. Block's slabs are contiguous -> cooperative
// float4 zero-fill, barrier, then per-thread band overwrites.
__launch_bounds__(256)
__global__ void fused(const float* __restrict__ x, Ptrs pt,
                      float* __restrict__ out, int B, int total) {
    const int tid = threadIdx.x;
    const int t   = blockIdx.x * 256 + tid;

    const size_t g1_off = (size_t)B * 20;
    const size_t f2_off = (size_t)B * 2420;
    const size_t g2_off = (size_t)B * 2540;

    // ---- cooperative zero-fill of this block's g1 + g2 slabs ----
    {
        int t0  = blockIdx.x * 256;
        int n_t = total - t0; if (n_t > 256) n_t = 256; if (n_t < 0) n_t = 0;
        float4 z4; z4.x = z4.y = z4.z = z4.w = 0.f;
        float4* z1 = reinterpret_cast<float4*>(out + g1_off + (size_t)t0 * 120);
        int c1 = n_t * 30;                       // float4 count in g1 slab
        for (int idx = tid; idx < c1; idx += 256) z1[idx] = z4;
        float4* z2 = reinterpret_cast<float4*>(out + g2_off + (size_t)t0 * 720);
        int c2 = n_t * 180;                      // float4 count in g2 slab
        for (int idx = tid; idx < c2; idx += 256) z2[idx] = z4;
    }
    __syncthreads();
    if (t >= total) return;

    const int b = t / U;
    const int i = t - b * U;

    const float* W1a = pt.p[0];  const float* b1a = pt.p[1];
    const float* W1b = pt.p[2];  const float* b1b = pt.p[3];
    const float* W1c = pt.p[4];  const float* b1c = pt.p[5];
    const float* W1d = pt.p[6];  const float* b1d = pt.p[7];
    const float* W2a = pt.p[8];  const float* b2a = pt.p[9];
    const float* W2b = pt.p[10]; const float* b2b = pt.p[11];
    const float* W2c = pt.p[12]; const float* b2c = pt.p[13];
    const float* W2d = pt.p[14]; const float* b2d = pt.p[15];

    float* g1row  = out + g1_off + (size_t)t * 120;
    float* g2rows = out + g2_off + (size_t)t * 720;

    // ---- stencil input ----
    const float* xb = x + (size_t)b * U;
    int im = (i == 0)     ? U - 1 : i - 1;
    int ip = (i == U - 1) ? 0     : i + 1;
    float v0 = xb[im], v1 = xb[i], v2 = xb[ip];

    float h1[16], h2[32], h3[16];

    // ================= MLP 1 =================
    #pragma unroll
    for (int n = 0; n < 16; n++)
        h1[n] = fmaxf(b1a[n] + v0 * W1a[n] + v1 * W1a[16 + n] + v2 * W1a[32 + n], 0.f);

    #pragma unroll
    for (int n = 0; n < 32; n++) h2[n] = b1b[n];
    #pragma unroll
    for (int k = 0; k < 16; k++) {
        float hk = h1[k];
        #pragma unroll
        for (int n = 0; n < 32; n++) h2[n] += hk * W1b[k * 32 + n];
    }
    #pragma unroll
    for (int n = 0; n < 32; n++) h2[n] = fmaxf(h2[n], 0.f);

    #pragma unroll
    for (int n = 0; n < 16; n++) h3[n] = b1c[n];
    #pragma unroll
    for (int k = 0; k < 32; k++) {
        float hk = h2[k];
        #pragma unroll
        for (int n = 0; n < 16; n++) h3[n] += hk * W1c[k * 16 + n];
    }
    #pragma unroll
    for (int n = 0; n < 16; n++) h3[n] = fmaxf(h3[n], 0.f);

    {
        float o1[19];
        #pragma unroll
        for (int n = 0; n < 19; n++) o1[n] = b1d[n];
        #pragma unroll
        for (int k = 0; k < 16; k++) {
            float hk = h3[k];
            #pragma unroll
            for (int n = 0; n < 19; n++) o1[n] += hk * W1d[k * 19 + n];
        }
        out[t] = gr(o1[0]);                       // f1
        #pragma unroll
        for (int j = 0; j < 3; j++) {             // g1 band: 3 chunks of 6
            int cc = i - 1 + j;
            if (cc < 0)  cc += U;
            if (cc >= U) cc -= U;
            float2* d = reinterpret_cast<float2*>(g1row + cc * 6);
            #pragma unroll
            for (int m = 0; m < 3; m++) {
                float2 v; v.x = gr(o1[1 + j * 6 + 2 * m]);
                          v.y = gr(o1[1 + j * 6 + 2 * m + 1]);
                d[m] = v;
            }
        }
    }

    // ================= MLP 2 =================
    #pragma unroll
    for (int n = 0; n < 16; n++)
        h1[n] = fmaxf(b2a[n] + v0 * W2a[n] + v1 * W2a[16 + n] + v2 * W2a[32 + n], 0.f);

    #pragma unroll
    for (int n = 0; n < 32; n++) h2[n] = b2b[n];
    #pragma unroll
    for (int k = 0; k < 16; k++) {
        float hk = h1[k];
        #pragma unroll
        for (int n = 0; n < 32; n++) h2[n] += hk * W2b[k * 32 + n];
    }
    #pragma unroll
    for (int n = 0; n < 32; n++) h2[n] = fmaxf(h2[n], 0.f);

    #pragma unroll
    for (int n = 0; n < 16; n++) h3[n] = b2c[n];
    #pragma unroll
    for (int k = 0; k < 32; k++) {
        float hk = h2[k];
        #pragma unroll
        for (int n = 0; n < 16; n++) h3[n] += hk * W2c[k * 16 + n];
    }
    #pragma unroll
    for (int n = 0; n < 16; n++) h3[n] = fmaxf(h3[n], 0.f);

    // f2: out2[:, :, 0:6] -> f2[t*6 + z]
    {
        float o2a[6];
        #pragma unroll
        for (int n = 0; n < 6; n++) o2a[n] = b2d[n];
        #pragma unroll
        for (int k = 0; k < 16; k++) {
            float hk = h3[k];
            #pragma unroll
            for (int n = 0; n < 6; n++) o2a[n] += hk * W2d[k * 186 + n];
        }
        float2* d = reinterpret_cast<float2*>(out + f2_off + (size_t)t * 6);
        #pragma unroll
        for (int m = 0; m < 3; m++) {
            float2 v; v.x = gr(o2a[2 * m]); v.y = gr(o2a[2 * m + 1]);
            d[m] = v;
        }
    }

    // g2: 6 rows; row z gets a 30-wide band in 5 chunks of 6 at ((i-2+j)%20)*6
    for (int z = 0; z < 6; z++) {
        float o2[30];
        #pragma unroll
        for (int n = 0; n < 30; n++) o2[n] = b2d[6 + z * 30 + n];
        #pragma unroll
        for (int k = 0; k < 16; k++) {
            float hk = h3[k];
            #pragma unroll
            for (int n = 0; n < 30; n++) o2[n] += hk * W2d[k * 186 + 6 + z * 30 + n];
        }
        float* row = g2rows + z * 120;
        #pragma unroll
        for (int j = 0; j < 5; j++) {
            int cc = i - 2 + j;
            if (cc < 0)  cc += U;
            if (cc >= U) cc -= U;
            float2* d = reinterpret_cast<float2*>(row + cc * 6);
            #pragma unroll
            for (int m = 0; m < 3; m++) {
                float2 v; v.x = gr(o2[j * 6 + 2 * m]);
                          v.y = gr(o2[j * 6 + 2 * m + 1]);
                d[m] = v;
            }
        }
    }
}

extern "C" void kernel_launch(void* const* d_in, const int* in_sizes, int n_in,
                              void* d_out, int out_size, void* d_ws, size_t ws_size,
                              hipStream_t stream) {
    const float* x = (const float*)d_in[0];
    Ptrs pt;
    for (int a = 0; a < 16; a++) pt.p[a] = (const float*)d_in[1 + a];

    int total = in_sizes[0];      // B * 20 (fp32 element count)
    int B = total / U;

    int blocks = (total + 255) / 256;
    fused<<<blocks, 256, 0, stream>>>(x, pt, (float*)d_out, B, total);
}